// Round 1
// baseline (1167.278 us; speedup 1.0000x reference)
//
#include <hip/hip_runtime.h>

// EGNN layer, fp32 vector implementation.
// B=4, N=16384, E=65536, DH=128, DM=64.
// Decomposition: edge first-layer pre-activations are computed per-NODE:
//   P[n] = [ h[n] @ pe_w1[0:128] | h[n] @ pe_w1[128:256] ]   (128 cols)
// so per edge: pre = P_top[src] + P_mid[dst] + dist2*pe_w1[256] + b1.

__device__ __forceinline__ float fast_rcp(float v) {
    return __builtin_amdgcn_rcpf(v);
}
__device__ __forceinline__ float fast_silu(float v) {
    // v * sigmoid(v); exp overflow -> rcp(inf)=0 -> silu=0, correct limit.
    return v * fast_rcp(1.0f + __expf(-v));
}

// ---------------------------------------------------------------------------
// init: out_x <- x (196608 floats), dh <- 0 (65536*64 floats)
// ---------------------------------------------------------------------------
__global__ __launch_bounds__(256) void init_k(const float* __restrict__ x,
                                              float* __restrict__ outx,
                                              float* __restrict__ dh) {
    int i = blockIdx.x * 256 + threadIdx.x;  // 0..1048575
    float4 z = make_float4(0.f, 0.f, 0.f, 0.f);
    ((float4*)dh)[i] = z;                     // exactly 1048576 float4
    if (i < 49152) ((float4*)outx)[i] = ((const float4*)x)[i];
}

// ---------------------------------------------------------------------------
// Tiled fp32 GEMM: out[M x 128] = f(A[M x KTOT] @ W[KTOT x 128] (+bias) (+resid))
// BM=128, BN=128, BK=64, 256 threads, 8x8 per-thread register tile.
// W1MODE: W column c<64 from pe_w1[k][c], c>=64 from pe_w1[128+k][c-64].
// HAS_A1: A k<128 from A0 (ld 128), k>=128 from A1 (ld 64)  (mlp1 concat).
// ---------------------------------------------------------------------------
template <int KTOT, bool W1MODE, bool HAS_A1, bool DO_SILU, bool HAS_BIAS, bool HAS_RESID>
__global__ __launch_bounds__(256, 2) void gemm_k(const float* __restrict__ A0,
                                                 const float* __restrict__ A1,
                                                 const float* __restrict__ W,
                                                 const float* __restrict__ bias,
                                                 const float* __restrict__ resid,
                                                 float* __restrict__ out) {
    constexpr int BM = 128, BN = 128, BK = 64, LDA = 132;  // LDA pad: 2-way-max banks, 16B aligned
    __shared__ float As[BK][LDA];   // col-major-ish: As[k][m]
    __shared__ float Ws[BK][BN];    // Ws[k][n]
    const int tid = threadIdx.x;
    const int m0 = blockIdx.x * BM;
    const int tc = (tid & 15) * 8;  // col offset
    const int tr = (tid >> 4) * 8;  // row offset
    float acc[8][8];
#pragma unroll
    for (int i = 0; i < 8; i++)
#pragma unroll
        for (int j = 0; j < 8; j++) acc[i][j] = 0.0f;

    for (int k0 = 0; k0 < KTOT; k0 += BK) {
        // stage A tile (128 rows x 64 k), transpose into As[k][m]
#pragma unroll
        for (int i = 0; i < 8; i++) {
            int lin = tid + i * 256;       // float4 granule 0..2047
            int m = lin >> 4;              // 0..127
            int k4 = (lin & 15) * 4;       // 0..60
            int k = k0 + k4;
            float4 v;
            if (!HAS_A1 || k < 128)        // uniform per k0-tile
                v = *(const float4*)(A0 + (size_t)(m0 + m) * 128 + k);
            else
                v = *(const float4*)(A1 + (size_t)(m0 + m) * 64 + (k - 128));
            As[k4 + 0][m] = v.x;
            As[k4 + 1][m] = v.y;
            As[k4 + 2][m] = v.z;
            As[k4 + 3][m] = v.w;
        }
        // stage W tile (64 k x 128 n)
#pragma unroll
        for (int i = 0; i < 8; i++) {
            int lin = tid + i * 256;
            int k = lin >> 5;              // 0..63
            int c = (lin & 31) * 4;        // 0..124
            float4 v;
            if (W1MODE) {
                if (c < 64) v = *(const float4*)(W + (size_t)(k0 + k) * 64 + c);
                else        v = *(const float4*)(W + (size_t)(128 + k0 + k) * 64 + (c - 64));
            } else {
                v = *(const float4*)(W + (size_t)(k0 + k) * BN + c);
            }
            *(float4*)&Ws[k][c] = v;
        }
        __syncthreads();
#pragma unroll 4
        for (int k = 0; k < BK; k++) {
            float4 a0 = *(const float4*)&As[k][tr];
            float4 a1 = *(const float4*)&As[k][tr + 4];
            float4 w0 = *(const float4*)&Ws[k][tc];
            float4 w1v = *(const float4*)&Ws[k][tc + 4];
            float a[8] = {a0.x, a0.y, a0.z, a0.w, a1.x, a1.y, a1.z, a1.w};
            float w[8] = {w0.x, w0.y, w0.z, w0.w, w1v.x, w1v.y, w1v.z, w1v.w};
#pragma unroll
            for (int i = 0; i < 8; i++)
#pragma unroll
                for (int j = 0; j < 8; j++) acc[i][j] = fmaf(a[i], w[j], acc[i][j]);
        }
        __syncthreads();
    }
    // epilogue
#pragma unroll
    for (int i = 0; i < 8; i++) {
        int m = m0 + tr + i;
        float vout[8];
#pragma unroll
        for (int j = 0; j < 8; j++) {
            float v = acc[i][j];
            if (HAS_BIAS) v += bias[tc + j];
            if (DO_SILU) v = fast_silu(v);
            if (HAS_RESID) v += resid[(size_t)m * 128 + tc + j];
            vout[j] = v;
        }
        float4* op = (float4*)(out + (size_t)m * 128 + tc);
        op[0] = make_float4(vout[0], vout[1], vout[2], vout[3]);
        op[1] = make_float4(vout[4], vout[5], vout[6], vout[7]);
    }
}

// ---------------------------------------------------------------------------
// edge kernel: one thread per edge (262144 total).
// m_k computed on the fly (no m[] array): s[64] accumulators only.
// W2 row reads are wave-uniform -> scalar-cache s_loads.
// ---------------------------------------------------------------------------
__global__ __launch_bounds__(256, 3) void edge_k(const float* __restrict__ x,
                                                 const float* __restrict__ P,
                                                 const int* __restrict__ ei,
                                                 const float* __restrict__ w1,
                                                 const float* __restrict__ b1,
                                                 const float* __restrict__ w2,
                                                 const float* __restrict__ b2,
                                                 const float* __restrict__ pxw,
                                                 float* __restrict__ dh,
                                                 float* __restrict__ outx) {
    const int e = blockIdx.x * 256 + threadIdx.x;  // exact: 262144 threads
    const int b = e >> 16;                          // e / E, E=65536
    const int2 sd = ((const int2*)ei)[e];           // (src, dst)
    const int gi = (b << 14) + sd.x;                // b*N + src
    const int gj = (b << 14) + sd.y;                // b*N + dst
    const float* xi = x + (size_t)gi * 3;
    const float* xj = x + (size_t)gj * 3;
    float dx = xi[0] - xj[0];
    float dy = xi[1] - xj[1];
    float dz = xi[2] - xj[2];
    float d2 = fmaxf(dx * dx + dy * dy + dz * dz, 1e-12f);

    const float* Pi = P + (size_t)gi * 128;         // h_i @ W1_top
    const float* Pj = P + (size_t)gj * 128 + 64;    // h_j @ W1_mid
    const float* w1r = w1 + 256 * 64;               // dist2 row of pe_w1

    float s[64];
#pragma unroll
    for (int j = 0; j < 64; j++) s[j] = b2[j];

#pragma unroll 2
    for (int k = 0; k < 64; k += 4) {
        float4 a = *(const float4*)(Pi + k);
        float4 c = *(const float4*)(Pj + k);
        float4 wr = *(const float4*)(w1r + k);
        float4 bb = *(const float4*)(b1 + k);
        float mk[4];
        mk[0] = fast_silu(a.x + c.x + d2 * wr.x + bb.x);
        mk[1] = fast_silu(a.y + c.y + d2 * wr.y + bb.y);
        mk[2] = fast_silu(a.z + c.z + d2 * wr.z + bb.z);
        mk[3] = fast_silu(a.w + c.w + d2 * wr.w + bb.w);
#pragma unroll
        for (int kk = 0; kk < 4; kk++) {
            const float* wrow = w2 + (size_t)(k + kk) * 64;  // wave-uniform
#pragma unroll
            for (int j = 0; j < 64; j++) s[j] = fmaf(mk[kk], wrow[j], s[j]);
        }
    }

    float mx = 0.0f;
    float* dhp = dh + (size_t)gi * 64;
#pragma unroll
    for (int j = 0; j < 64; j++) {
        float mij = fast_silu(s[j]);
        mx = fmaf(mij, pxw[j], mx);
        atomicAdd(dhp + j, mij);
    }
    float sc = mx * fast_rcp(sqrtf(d2) + 1e-8f);
    size_t xo = (size_t)gi * 3;
    atomicAdd(outx + xo + 0, sc * dx);
    atomicAdd(outx + xo + 1, sc * dy);
    atomicAdd(outx + xo + 2, sc * dz);
}

// ---------------------------------------------------------------------------
extern "C" void kernel_launch(void* const* d_in, const int* in_sizes, int n_in,
                              void* d_out, int out_size, void* d_ws, size_t ws_size,
                              hipStream_t stream) {
    const float* x     = (const float*)d_in[0];
    const float* h     = (const float*)d_in[1];
    const int*   ei    = (const int*)d_in[2];
    const float* pe_w1 = (const float*)d_in[3];
    const float* pe_b1 = (const float*)d_in[4];
    const float* pe_w2 = (const float*)d_in[5];
    const float* pe_b2 = (const float*)d_in[6];
    const float* px_w  = (const float*)d_in[7];
    const float* ph_w1 = (const float*)d_in[8];
    const float* ph_b1 = (const float*)d_in[9];
    const float* ph_w2 = (const float*)d_in[10];
    const float* ph_b2 = (const float*)d_in[11];

    float* outx = (float*)d_out;                    // 4*16384*3
    float* outh = (float*)d_out + 196608;           // 4*16384*128
    float* P    = (float*)d_ws;                     // 65536*128 (reused as t)
    float* dh   = P + (size_t)65536 * 128;          // 65536*64

    // 1) init out_x = x, dh = 0
    init_k<<<4096, 256, 0, stream>>>(x, outx, dh);
    // 2) P = h @ [W1_top | W1_mid]
    gemm_k<128, true, false, false, false, false>
        <<<512, 256, 0, stream>>>(h, nullptr, pe_w1, nullptr, nullptr, P);
    // 3) edge MLP + scatters
    edge_k<<<1024, 256, 0, stream>>>(x, P, ei, pe_w1, pe_b1, pe_w2, pe_b2,
                                     px_w, dh, outx);
    // 4) t = silu([h | dh] @ ph_w1 + b1)   (overwrites P)
    gemm_k<192, false, true, true, true, false>
        <<<512, 256, 0, stream>>>(h, dh, ph_w1, ph_b1, nullptr, P);
    // 5) out_h = h + t @ ph_w2 + b2
    gemm_k<128, false, false, false, true, true>
        <<<512, 256, 0, stream>>>(P, nullptr, ph_w2, ph_b2, h, outh);
}

// Round 2
// 335.995 us; speedup vs baseline: 3.4741x; 3.4741x over previous
//
#include <hip/hip_runtime.h>

// EGNN layer, round 2: CSR gather replaces fp32 atomic scatter.
// B=4, N=16384, E=65536, DH=128, DM=64.  NB = B*N = 65536 global nodes.
// P[n] = [ h[n] @ pe_w1[0:128] | h[n] @ pe_w1[128:256] ]  (128 cols)
// per edge: pre_k = P_top[src][k] + P_mid[dst][k] + dist2*pe_w1[256][k] + b1[k]

__device__ __forceinline__ float fast_rcp(float v) {
    return __builtin_amdgcn_rcpf(v);
}
__device__ __forceinline__ float fast_silu(float v) {
    return v * fast_rcp(1.0f + __expf(-v));
}

// ---------------------------------------------------------------------------
// zero deg[] and cursor[] (65536 ints each) — ws is poisoned every call
// ---------------------------------------------------------------------------
__global__ __launch_bounds__(256) void zero_k(int* __restrict__ deg,
                                              int* __restrict__ cursor) {
    int i = blockIdx.x * 256 + threadIdx.x;  // 65536 threads
    deg[i] = 0;
    cursor[i] = 0;
}

// ---------------------------------------------------------------------------
// histogram: deg[src]++  (int atomics, avg contention = 4)
// ---------------------------------------------------------------------------
__global__ __launch_bounds__(256) void hist_k(const int* __restrict__ ei,
                                              int* __restrict__ deg) {
    int e = blockIdx.x * 256 + threadIdx.x;  // 262144 threads
    int2 sd = ((const int2*)ei)[e];
    int gi = ((e >> 16) << 14) + sd.x;
    atomicAdd(&deg[gi], 1);
}

// ---------------------------------------------------------------------------
// exclusive scan of deg[65536] -> rowstart[65536]; single block, 1024 thr
// ---------------------------------------------------------------------------
__global__ __launch_bounds__(1024) void scan_k(const int* __restrict__ deg,
                                               int* __restrict__ rowstart) {
    __shared__ int ts[1024];
    const int t = threadIdx.x;
    const int base = t * 64;
    int s = 0;
#pragma unroll 8
    for (int i = 0; i < 64; i++) s += deg[base + i];
    ts[t] = s;
    __syncthreads();
    // Hillis-Steele inclusive scan over 1024 chunk sums
    for (int off = 1; off < 1024; off <<= 1) {
        int v = ts[t];
        int add = (t >= off) ? ts[t - off] : 0;
        __syncthreads();
        ts[t] = v + add;
        __syncthreads();
    }
    int run = (t == 0) ? 0 : ts[t - 1];
#pragma unroll 8
    for (int i = 0; i < 64; i++) {
        rowstart[base + i] = run;
        run += deg[base + i];
    }
}

// ---------------------------------------------------------------------------
// scatter edge dst indices into CSR slots: elist[rowstart[src] + slot] = gj
// ---------------------------------------------------------------------------
__global__ __launch_bounds__(256) void scatter_k(const int* __restrict__ ei,
                                                 const int* __restrict__ rowstart,
                                                 int* __restrict__ cursor,
                                                 int* __restrict__ elist) {
    int e = blockIdx.x * 256 + threadIdx.x;
    int2 sd = ((const int2*)ei)[e];
    int b = e >> 16;
    int gi = (b << 14) + sd.x;
    int gj = (b << 14) + sd.y;
    int slot = atomicAdd(&cursor[gi], 1);
    elist[rowstart[gi] + slot] = gj;
}

// ---------------------------------------------------------------------------
// node kernel: one wave (64 lanes) per node; lane = feature index.
// Recomputes edge MLP per incident edge; no atomics, coalesced final writes.
// W2 column `lane` lives in 64 VGPRs; m broadcast via 64B LDS (1-wave block).
// ---------------------------------------------------------------------------
__global__ __launch_bounds__(64) void node_k(const float* __restrict__ x,
                                             const float* __restrict__ P,
                                             const int* __restrict__ rowstart,
                                             const int* __restrict__ deg,
                                             const int* __restrict__ elist,
                                             const float* __restrict__ w1,
                                             const float* __restrict__ b1,
                                             const float* __restrict__ w2,
                                             const float* __restrict__ b2,
                                             const float* __restrict__ pxw,
                                             float* __restrict__ dh,
                                             float* __restrict__ outx) {
    const int n = blockIdx.x;        // 0..65535 global node
    const int lane = threadIdx.x;    // 0..63
    __shared__ float m_lds[64];

    float w2c[64];                   // w2[:, lane]
#pragma unroll
    for (int k = 0; k < 64; k++) w2c[k] = w2[k * 64 + lane];
    const float w1r = w1[256 * 64 + lane];   // dist2 row
    const float b1v = b1[lane];
    const float b2v = b2[lane];
    const float pxv = pxw[lane];
    const float Pi = P[(size_t)n * 128 + lane];   // top half, k=lane
    const float xi0 = x[n * 3 + 0];
    const float xi1 = x[n * 3 + 1];
    const float xi2 = x[n * 3 + 2];

    float dhacc = 0.0f;
    float dxp0 = 0.0f, dxp1 = 0.0f, dxp2 = 0.0f;
    const int start = rowstart[n];
    const int dg = deg[n];

    for (int t = 0; t < dg; t++) {
        int gj = elist[start + t];                       // wave-uniform
        float Pj = P[(size_t)gj * 128 + 64 + lane];      // coalesced 256B gather
        float ddx = xi0 - x[gj * 3 + 0];
        float ddy = xi1 - x[gj * 3 + 1];
        float ddz = xi2 - x[gj * 3 + 2];
        float d2 = fmaxf(ddx * ddx + ddy * ddy + ddz * ddz, 1e-12f);
        float m = fast_silu(Pi + Pj + d2 * w1r + b1v);
        __syncthreads();                                 // 1-wave block: free
        m_lds[lane] = m;
        __syncthreads();
        float s = b2v;
#pragma unroll
        for (int k = 0; k < 64; k += 4) {
            float4 mv = *(const float4*)&m_lds[k];       // broadcast read
            s = fmaf(mv.x, w2c[k + 0], s);
            s = fmaf(mv.y, w2c[k + 1], s);
            s = fmaf(mv.z, w2c[k + 2], s);
            s = fmaf(mv.w, w2c[k + 3], s);
        }
        float m2 = fast_silu(s);
        dhacc += m2;
        float invd = fast_rcp(sqrtf(d2) + 1e-8f);
        float c = m2 * pxv * invd;
        dxp0 = fmaf(c, ddx, dxp0);
        dxp1 = fmaf(c, ddy, dxp1);
        dxp2 = fmaf(c, ddz, dxp2);
    }

    dh[(size_t)n * 64 + lane] = dhacc;                   // coalesced

    // reduce dx partials across the wave
    for (int off = 32; off; off >>= 1) {
        dxp0 += __shfl_down(dxp0, off);
        dxp1 += __shfl_down(dxp1, off);
        dxp2 += __shfl_down(dxp2, off);
    }
    if (lane == 0) {
        outx[n * 3 + 0] = xi0 + dxp0;
        outx[n * 3 + 1] = xi1 + dxp1;
        outx[n * 3 + 2] = xi2 + dxp2;
    }
}

// ---------------------------------------------------------------------------
// Tiled fp32 GEMM (unchanged from round 1)
// ---------------------------------------------------------------------------
template <int KTOT, bool W1MODE, bool HAS_A1, bool DO_SILU, bool HAS_BIAS, bool HAS_RESID>
__global__ __launch_bounds__(256, 2) void gemm_k(const float* __restrict__ A0,
                                                 const float* __restrict__ A1,
                                                 const float* __restrict__ W,
                                                 const float* __restrict__ bias,
                                                 const float* __restrict__ resid,
                                                 float* __restrict__ out) {
    constexpr int BM = 128, BN = 128, BK = 64, LDA = 132;
    __shared__ float As[BK][LDA];
    __shared__ float Ws[BK][BN];
    const int tid = threadIdx.x;
    const int m0 = blockIdx.x * BM;
    const int tc = (tid & 15) * 8;
    const int tr = (tid >> 4) * 8;
    float acc[8][8];
#pragma unroll
    for (int i = 0; i < 8; i++)
#pragma unroll
        for (int j = 0; j < 8; j++) acc[i][j] = 0.0f;

    for (int k0 = 0; k0 < KTOT; k0 += BK) {
#pragma unroll
        for (int i = 0; i < 8; i++) {
            int lin = tid + i * 256;
            int m = lin >> 4;
            int k4 = (lin & 15) * 4;
            int k = k0 + k4;
            float4 v;
            if (!HAS_A1 || k < 128)
                v = *(const float4*)(A0 + (size_t)(m0 + m) * 128 + k);
            else
                v = *(const float4*)(A1 + (size_t)(m0 + m) * 64 + (k - 128));
            As[k4 + 0][m] = v.x;
            As[k4 + 1][m] = v.y;
            As[k4 + 2][m] = v.z;
            As[k4 + 3][m] = v.w;
        }
#pragma unroll
        for (int i = 0; i < 8; i++) {
            int lin = tid + i * 256;
            int k = lin >> 5;
            int c = (lin & 31) * 4;
            float4 v;
            if (W1MODE) {
                if (c < 64) v = *(const float4*)(W + (size_t)(k0 + k) * 64 + c);
                else        v = *(const float4*)(W + (size_t)(128 + k0 + k) * 64 + (c - 64));
            } else {
                v = *(const float4*)(W + (size_t)(k0 + k) * BN + c);
            }
            *(float4*)&Ws[k][c] = v;
        }
        __syncthreads();
#pragma unroll 4
        for (int k = 0; k < BK; k++) {
            float4 a0 = *(const float4*)&As[k][tr];
            float4 a1 = *(const float4*)&As[k][tr + 4];
            float4 w0 = *(const float4*)&Ws[k][tc];
            float4 w1v = *(const float4*)&Ws[k][tc + 4];
            float a[8] = {a0.x, a0.y, a0.z, a0.w, a1.x, a1.y, a1.z, a1.w};
            float w[8] = {w0.x, w0.y, w0.z, w0.w, w1v.x, w1v.y, w1v.z, w1v.w};
#pragma unroll
            for (int i = 0; i < 8; i++)
#pragma unroll
                for (int j = 0; j < 8; j++) acc[i][j] = fmaf(a[i], w[j], acc[i][j]);
        }
        __syncthreads();
    }
#pragma unroll
    for (int i = 0; i < 8; i++) {
        int m = m0 + tr + i;
        float vout[8];
#pragma unroll
        for (int j = 0; j < 8; j++) {
            float v = acc[i][j];
            if (HAS_BIAS) v += bias[tc + j];
            if (DO_SILU) v = fast_silu(v);
            if (HAS_RESID) v += resid[(size_t)m * 128 + tc + j];
            vout[j] = v;
        }
        float4* op = (float4*)(out + (size_t)m * 128 + tc);
        op[0] = make_float4(vout[0], vout[1], vout[2], vout[3]);
        op[1] = make_float4(vout[4], vout[5], vout[6], vout[7]);
    }
}

// ---------------------------------------------------------------------------
extern "C" void kernel_launch(void* const* d_in, const int* in_sizes, int n_in,
                              void* d_out, int out_size, void* d_ws, size_t ws_size,
                              hipStream_t stream) {
    const float* x     = (const float*)d_in[0];
    const float* h     = (const float*)d_in[1];
    const int*   ei    = (const int*)d_in[2];
    const float* pe_w1 = (const float*)d_in[3];
    const float* pe_b1 = (const float*)d_in[4];
    const float* pe_w2 = (const float*)d_in[5];
    const float* pe_b2 = (const float*)d_in[6];
    const float* px_w  = (const float*)d_in[7];
    const float* ph_w1 = (const float*)d_in[8];
    const float* ph_b1 = (const float*)d_in[9];
    const float* ph_w2 = (const float*)d_in[10];
    const float* ph_b2 = (const float*)d_in[11];

    float* outx = (float*)d_out;                    // 4*16384*3
    float* outh = (float*)d_out + 196608;           // 4*16384*128

    // ws layout (49.75 MB)
    float* P       = (float*)d_ws;                        // 65536*128 f32 (reused as t)
    float* dh      = P + (size_t)65536 * 128;             // 65536*64 f32
    int*   deg     = (int*)(dh + (size_t)65536 * 64);     // 65536 i32
    int*   rowstart= deg + 65536;                         // 65536 i32
    int*   cursor  = rowstart + 65536;                    // 65536 i32
    int*   elist   = cursor + 65536;                      // 262144 i32

    zero_k<<<256, 256, 0, stream>>>(deg, cursor);
    gemm_k<128, true, false, false, false, false>
        <<<512, 256, 0, stream>>>(h, nullptr, pe_w1, nullptr, nullptr, P);
    hist_k<<<1024, 256, 0, stream>>>(ei, deg);
    scan_k<<<1, 1024, 0, stream>>>(deg, rowstart);
    scatter_k<<<1024, 256, 0, stream>>>(ei, rowstart, cursor, elist);
    node_k<<<65536, 64, 0, stream>>>(x, P, rowstart, deg, elist,
                                     pe_w1, pe_b1, pe_w2, pe_b2, px_w,
                                     dh, outx);
    gemm_k<192, false, true, true, true, false>
        <<<512, 256, 0, stream>>>(h, dh, ph_w1, ph_b1, nullptr, P);
    gemm_k<128, false, false, false, true, true>
        <<<512, 256, 0, stream>>>(P, nullptr, ph_w2, ph_b2, h, outh);
}

// Round 3
// 305.606 us; speedup vs baseline: 3.8195x; 1.0994x over previous
//
#include <hip/hip_runtime.h>

// EGNN layer, round 3: bf16-MFMA GEMMs + register-resident W2 in node kernel.
// B=4, N=16384, E=65536, DH=128, DM=64.  NB = 65536 global nodes.
// P[n] = [ h[n] @ pe_w1[0:128] | h[n] @ pe_w1[128:256] ]  (128 cols, bf16)

typedef unsigned short ushort_t;
typedef __attribute__((ext_vector_type(8))) short bf16x8;   // 8 bf16 = 4 VGPRs
typedef __attribute__((ext_vector_type(4))) float f32x4;

__device__ __forceinline__ float fast_rcp(float v) { return __builtin_amdgcn_rcpf(v); }
__device__ __forceinline__ float fast_silu(float v) { return v * fast_rcp(1.0f + __expf(-v)); }
__device__ __forceinline__ ushort_t f2bf(float f) {   // RNE fp32->bf16 (finite inputs)
    unsigned u = __float_as_uint(f);
    u += 0x7fffu + ((u >> 16) & 1u);
    return (ushort_t)(u >> 16);
}
__device__ __forceinline__ float bf2f(ushort_t b) {
    return __uint_as_float(((unsigned)b) << 16);
}

// ---------------------------------------------------------------------------
// zero deg[] and cursor[]
// ---------------------------------------------------------------------------
__global__ __launch_bounds__(256) void zero_k(int* __restrict__ deg,
                                              int* __restrict__ cursor) {
    int i = blockIdx.x * 256 + threadIdx.x;
    deg[i] = 0;
    cursor[i] = 0;
}

// ---------------------------------------------------------------------------
// histogram: deg[src]++
// ---------------------------------------------------------------------------
__global__ __launch_bounds__(256) void hist_k(const int* __restrict__ ei,
                                              int* __restrict__ deg) {
    int e = blockIdx.x * 256 + threadIdx.x;
    int2 sd = ((const int2*)ei)[e];
    int gi = ((e >> 16) << 14) + sd.x;
    atomicAdd(&deg[gi], 1);
}

// ---------------------------------------------------------------------------
// exclusive scan of deg[65536] -> rowstart[65536]; single block, 1024 thr
// ---------------------------------------------------------------------------
__global__ __launch_bounds__(1024) void scan_k(const int* __restrict__ deg,
                                               int* __restrict__ rowstart) {
    __shared__ int ts[1024];
    const int t = threadIdx.x;
    const int base = t * 64;
    int s = 0;
#pragma unroll 8
    for (int i = 0; i < 64; i++) s += deg[base + i];
    ts[t] = s;
    __syncthreads();
    for (int off = 1; off < 1024; off <<= 1) {
        int v = ts[t];
        int add = (t >= off) ? ts[t - off] : 0;
        __syncthreads();
        ts[t] = v + add;
        __syncthreads();
    }
    int run = (t == 0) ? 0 : ts[t - 1];
#pragma unroll 8
    for (int i = 0; i < 64; i++) {
        rowstart[base + i] = run;
        run += deg[base + i];
    }
}

// ---------------------------------------------------------------------------
// scatter edge dst indices into CSR slots
// ---------------------------------------------------------------------------
__global__ __launch_bounds__(256) void scatter_k(const int* __restrict__ ei,
                                                 const int* __restrict__ rowstart,
                                                 int* __restrict__ cursor,
                                                 int* __restrict__ elist) {
    int e = blockIdx.x * 256 + threadIdx.x;
    int2 sd = ((const int2*)ei)[e];
    int b = e >> 16;
    int gi = (b << 14) + sd.x;
    int gj = (b << 14) + sd.y;
    int slot = atomicAdd(&cursor[gi], 1);
    elist[rowstart[gi] + slot] = gj;
}

// ---------------------------------------------------------------------------
// node kernel: one wave per node; lane = feature. P is bf16 now; dh out bf16.
// __launch_bounds__(64,4): VGPR cap 128 so w2c[64] stays register-resident.
// ---------------------------------------------------------------------------
__global__ __launch_bounds__(64, 4) void node_k(const float* __restrict__ x,
                                                const ushort_t* __restrict__ P,
                                                const int* __restrict__ rowstart,
                                                const int* __restrict__ deg,
                                                const int* __restrict__ elist,
                                                const float* __restrict__ w1,
                                                const float* __restrict__ b1,
                                                const float* __restrict__ w2,
                                                const float* __restrict__ b2,
                                                const float* __restrict__ pxw,
                                                ushort_t* __restrict__ dh,
                                                float* __restrict__ outx) {
    const int n = blockIdx.x;
    const int lane = threadIdx.x;
    __shared__ float m_lds[64];

    float w2c[64];                   // w2[:, lane] — register resident
#pragma unroll
    for (int k = 0; k < 64; k++) w2c[k] = w2[k * 64 + lane];
    const float w1r = w1[256 * 64 + lane];
    const float b1v = b1[lane];
    const float b2v = b2[lane];
    const float pxv = pxw[lane];
    const float Pi = bf2f(P[(size_t)n * 128 + lane]);
    const float xi0 = x[n * 3 + 0];
    const float xi1 = x[n * 3 + 1];
    const float xi2 = x[n * 3 + 2];

    float dhacc = 0.0f;
    float dxp0 = 0.0f, dxp1 = 0.0f, dxp2 = 0.0f;
    const int start = rowstart[n];
    const int dg = deg[n];

    for (int t = 0; t < dg; t++) {
        int gj = elist[start + t];                           // wave-uniform
        float Pj = bf2f(P[(size_t)gj * 128 + 64 + lane]);    // 128B/wave gather
        float ddx = xi0 - x[gj * 3 + 0];
        float ddy = xi1 - x[gj * 3 + 1];
        float ddz = xi2 - x[gj * 3 + 2];
        float d2 = fmaxf(ddx * ddx + ddy * ddy + ddz * ddz, 1e-12f);
        float m = fast_silu(Pi + Pj + d2 * w1r + b1v);
        __syncthreads();
        m_lds[lane] = m;
        __syncthreads();
        float s = b2v;
#pragma unroll
        for (int k = 0; k < 64; k += 4) {
            float4 mv = *(const float4*)&m_lds[k];
            s = fmaf(mv.x, w2c[k + 0], s);
            s = fmaf(mv.y, w2c[k + 1], s);
            s = fmaf(mv.z, w2c[k + 2], s);
            s = fmaf(mv.w, w2c[k + 3], s);
        }
        float m2 = fast_silu(s);
        dhacc += m2;
        float invd = fast_rcp(sqrtf(d2) + 1e-8f);
        float c = m2 * pxv * invd;
        dxp0 = fmaf(c, ddx, dxp0);
        dxp1 = fmaf(c, ddy, dxp1);
        dxp2 = fmaf(c, ddz, dxp2);
    }

    dh[(size_t)n * 64 + lane] = f2bf(dhacc);

    for (int off = 32; off; off >>= 1) {
        dxp0 += __shfl_down(dxp0, off);
        dxp1 += __shfl_down(dxp1, off);
        dxp2 += __shfl_down(dxp2, off);
    }
    if (lane == 0) {
        outx[n * 3 + 0] = xi0 + dxp0;
        outx[n * 3 + 1] = xi1 + dxp1;
        outx[n * 3 + 2] = xi2 + dxp2;
    }
}

// ---------------------------------------------------------------------------
// bf16 MFMA GEMM: out[M x 128] = f(A[M x KTOT] @ W[KTOT x 128] (+b)(+resid))
// 256 thr = 4 waves; block tile 128x128; wave tile 32x128 = 2x8 mfma 16x16x32.
// fp32->bf16 convert fused into LDS staging. KPAD=40 (2-way-max banks, 16B ok).
// A/B/C layouts per m89-verified mapping:
//   A: lane holds A[m=lane&15][k=(lane>>4)*8 + j]  (8 contig bf16 -> b128)
//   B: lane holds B[k=(lane>>4)*8 + j][n=lane&15]  (Wt[n][k] k-contig in LDS)
//   D: col=lane&15, row=(lane>>4)*4 + reg
// ---------------------------------------------------------------------------
template <int KTOT, bool W1MODE, bool A0_BF16, bool HAS_A1, bool DO_SILU,
          bool HAS_BIAS, bool HAS_RESID, bool OUT_BF16>
__global__ __launch_bounds__(256, 2) void mgemm_k(const void* __restrict__ A0v,
                                                  const ushort_t* __restrict__ A1,
                                                  const float* __restrict__ W,
                                                  const float* __restrict__ bias,
                                                  const float* __restrict__ resid,
                                                  void* __restrict__ outv) {
    constexpr int KPAD = 40;
    __shared__ ushort_t As[128 * KPAD];
    __shared__ ushort_t Bs[128 * KPAD];
    const int tid = threadIdx.x;
    const int m0 = blockIdx.x * 128;
    const int wave = tid >> 6;
    const int lane = tid & 63;
    const int lr = lane & 15;
    const int lq = lane >> 4;

    f32x4 acc[2][8];
#pragma unroll
    for (int mt = 0; mt < 2; mt++)
#pragma unroll
        for (int nt = 0; nt < 8; nt++) {
            f32x4 z = {0.f, 0.f, 0.f, 0.f};
            acc[mt][nt] = z;
        }

    for (int k0 = 0; k0 < KTOT; k0 += 32) {
        // stage A tile: 128 rows x 32 k -> bf16 LDS (row-major, k contiguous)
#pragma unroll
        for (int i = 0; i < 4; i++) {
            int lin = tid + i * 256;       // 0..1023 granules of 4 elems
            int m = lin >> 3;              // 0..127
            int kq = (lin & 7) * 4;        // 0..28
            ushort4 w4;
            if (HAS_A1 && k0 >= 128) {
                w4 = *(const ushort4*)(A1 + (size_t)(m0 + m) * 64 + (k0 - 128 + kq));
            } else if (A0_BF16) {
                w4 = *(const ushort4*)((const ushort_t*)A0v + (size_t)(m0 + m) * 128 + k0 + kq);
            } else {
                float4 v = *(const float4*)((const float*)A0v + (size_t)(m0 + m) * 128 + k0 + kq);
                w4.x = f2bf(v.x); w4.y = f2bf(v.y); w4.z = f2bf(v.z); w4.w = f2bf(v.w);
            }
            *(ushort4*)&As[m * KPAD + kq] = w4;
        }
        // stage W^T tile: Bs[n][k], n=0..127, k=0..31
#pragma unroll
        for (int i = 0; i < 16; i++) {
            int lin = tid + i * 256;       // 0..4095
            int n = lin >> 5;
            int k = lin & 31;
            float wv;
            if (W1MODE) {
                wv = (n < 64) ? W[(size_t)(k0 + k) * 64 + n]
                              : W[(size_t)(128 + k0 + k) * 64 + (n - 64)];
            } else {
                wv = W[(size_t)(k0 + k) * 128 + n];
            }
            Bs[n * KPAD + k] = f2bf(wv);
        }
        __syncthreads();

        bf16x8 af[2], bfr[8];
#pragma unroll
        for (int mt = 0; mt < 2; mt++) {
            int row = wave * 32 + mt * 16 + lr;
            af[mt] = *(const bf16x8*)&As[row * KPAD + lq * 8];
        }
#pragma unroll
        for (int nt = 0; nt < 8; nt++) {
            int nn = nt * 16 + lr;
            bfr[nt] = *(const bf16x8*)&Bs[nn * KPAD + lq * 8];
        }
#pragma unroll
        for (int mt = 0; mt < 2; mt++)
#pragma unroll
            for (int nt = 0; nt < 8; nt++)
                acc[mt][nt] = __builtin_amdgcn_mfma_f32_16x16x32_bf16(
                    af[mt], bfr[nt], acc[mt][nt], 0, 0, 0);
        __syncthreads();
    }

    // epilogue
#pragma unroll
    for (int mt = 0; mt < 2; mt++) {
#pragma unroll
        for (int nt = 0; nt < 8; nt++) {
#pragma unroll
            for (int r = 0; r < 4; r++) {
                int row = m0 + wave * 32 + mt * 16 + lq * 4 + r;
                int col = nt * 16 + lr;
                float v = acc[mt][nt][r];
                if (HAS_BIAS) v += bias[col];
                if (DO_SILU) v = fast_silu(v);
                if (HAS_RESID) v += resid[(size_t)row * 128 + col];
                if (OUT_BF16)
                    ((ushort_t*)outv)[(size_t)row * 128 + col] = f2bf(v);
                else
                    ((float*)outv)[(size_t)row * 128 + col] = v;
            }
        }
    }
}

// ---------------------------------------------------------------------------
extern "C" void kernel_launch(void* const* d_in, const int* in_sizes, int n_in,
                              void* d_out, int out_size, void* d_ws, size_t ws_size,
                              hipStream_t stream) {
    const float* x     = (const float*)d_in[0];
    const float* h     = (const float*)d_in[1];
    const int*   ei    = (const int*)d_in[2];
    const float* pe_w1 = (const float*)d_in[3];
    const float* pe_b1 = (const float*)d_in[4];
    const float* pe_w2 = (const float*)d_in[5];
    const float* pe_b2 = (const float*)d_in[6];
    const float* px_w  = (const float*)d_in[7];
    const float* ph_w1 = (const float*)d_in[8];
    const float* ph_b1 = (const float*)d_in[9];
    const float* ph_w2 = (const float*)d_in[10];
    const float* ph_b2 = (const float*)d_in[11];

    float* outx = (float*)d_out;                    // 4*16384*3
    float* outh = (float*)d_out + 196608;           // 4*16384*128

    // ws layout
    ushort_t* P   = (ushort_t*)d_ws;                      // 65536*128 bf16 (reused as t)
    ushort_t* dh  = P + (size_t)65536 * 128;              // 65536*64 bf16
    int* deg      = (int*)(dh + (size_t)65536 * 64);      // 65536 i32
    int* rowstart = deg + 65536;
    int* cursor   = rowstart + 65536;
    int* elist    = cursor + 65536;                       // 262144 i32

    zero_k<<<256, 256, 0, stream>>>(deg, cursor);
    // P = h @ [W1_top | W1_mid]  (bf16 out)
    mgemm_k<128, true, false, false, false, false, false, true>
        <<<512, 256, 0, stream>>>(h, nullptr, pe_w1, nullptr, nullptr, P);
    hist_k<<<1024, 256, 0, stream>>>(ei, deg);
    scan_k<<<1, 1024, 0, stream>>>(deg, rowstart);
    scatter_k<<<1024, 256, 0, stream>>>(ei, rowstart, cursor, elist);
    node_k<<<65536, 64, 0, stream>>>(x, P, rowstart, deg, elist,
                                     pe_w1, pe_b1, pe_w2, pe_b2, px_w,
                                     dh, outx);
    // t = silu([h | dh] @ ph_w1 + b1)  (bf16 out, overwrites P)
    mgemm_k<192, false, false, true, true, true, false, true>
        <<<512, 256, 0, stream>>>(h, dh, ph_w1, ph_b1, nullptr, P);
    // out_h = h + t @ ph_w2 + b2  (fp32 out)
    mgemm_k<128, false, true, false, false, true, true, false>
        <<<512, 256, 0, stream>>>(P, nullptr, ph_w2, ph_b2, h, outh);
}

// Round 4
// 297.772 us; speedup vs baseline: 3.9200x; 1.0263x over previous
//
#include <hip/hip_runtime.h>

// EGNN layer, round 4: no scan (stride-bucket CSR), register-resident W2,
// pre-transposed bf16 weights for MFMA GEMMs.
// B=4, N=16384, E=65536, DH=128, DM=64.  NB = 65536 global nodes. STRIDE=64.

typedef unsigned short ushort_t;
typedef __attribute__((ext_vector_type(8))) short bf16x8;
typedef __attribute__((ext_vector_type(4))) float f32x4;

__device__ __forceinline__ float fast_rcp(float v) { return __builtin_amdgcn_rcpf(v); }
__device__ __forceinline__ float fast_silu(float v) { return v * fast_rcp(1.0f + __expf(-v)); }
__device__ __forceinline__ ushort_t f2bf(float f) {
    unsigned u = __float_as_uint(f);
    u += 0x7fffu + ((u >> 16) & 1u);
    return (ushort_t)(u >> 16);
}
__device__ __forceinline__ float bf2f(ushort_t b) {
    return __uint_as_float(((unsigned)b) << 16);
}

// ---------------------------------------------------------------------------
// zero cursor[65536]
// ---------------------------------------------------------------------------
__global__ __launch_bounds__(256) void zero_k(int* __restrict__ cursor) {
    cursor[blockIdx.x * 256 + threadIdx.x] = 0;
}

// ---------------------------------------------------------------------------
// prep: transpose weights.  61440 threads total (240 blocks x 256).
//  seg A: W1t  bf16[128][128]  W1t[c*128+k]   = pe_w1 fused cols
//  seg B: Wp1t bf16[128][192]  Wp1t[n*192+k]  = ph_w1[k][n]
//  seg C: Wp2t bf16[128][128]  Wp2t[n*128+k]  = ph_w2[k][n]
//  seg D: w2t  f32 [64][64]    w2t[c*64+k]    = pe_w2[k][c]
// ---------------------------------------------------------------------------
__global__ __launch_bounds__(256) void prep_k(const float* __restrict__ pe_w1,
                                              const float* __restrict__ pe_w2,
                                              const float* __restrict__ ph_w1,
                                              const float* __restrict__ ph_w2,
                                              ushort_t* __restrict__ W1t,
                                              ushort_t* __restrict__ Wp1t,
                                              ushort_t* __restrict__ Wp2t,
                                              float* __restrict__ w2t) {
    int g = blockIdx.x * 256 + threadIdx.x;
    if (g < 16384) {
        int c = g >> 7, k = g & 127;
        float v = (c < 64) ? pe_w1[k * 64 + c] : pe_w1[(128 + k) * 64 + (c - 64)];
        W1t[g] = f2bf(v);
    } else if (g < 16384 + 24576) {
        int g2 = g - 16384;
        int n = g2 / 192, k = g2 - n * 192;
        Wp1t[g2] = f2bf(ph_w1[k * 128 + n]);
    } else if (g < 16384 + 24576 + 16384) {
        int g3 = g - 40960;
        int n = g3 >> 7, k = g3 & 127;
        Wp2t[g3] = f2bf(ph_w2[k * 128 + n]);
    } else if (g < 16384 + 24576 + 16384 + 4096) {
        int g4 = g - 57344;
        int c = g4 >> 6, k = g4 & 63;
        w2t[g4] = pe_w2[k * 64 + c];
    }
}

// ---------------------------------------------------------------------------
// scatter: elist[gi*64 + slot] = gj  (no scan needed; deg max ~18 << 64)
// ---------------------------------------------------------------------------
__global__ __launch_bounds__(256) void scatter_k(const int* __restrict__ ei,
                                                 int* __restrict__ cursor,
                                                 int* __restrict__ elist) {
    int e = blockIdx.x * 256 + threadIdx.x;
    int2 sd = ((const int2*)ei)[e];
    int b = e >> 16;
    int gi = (b << 14) + sd.x;
    int gj = (b << 14) + sd.y;
    int slot = atomicAdd(&cursor[gi], 1);
    if (slot < 64) elist[gi * 64 + slot] = gj;
}

// ---------------------------------------------------------------------------
// node kernel: one wave per node; lane = feature.
// w2 column -> 16 NAMED float4 registers (from w2t rows). 4 accumulators.
// Wave-synchronous LDS m-broadcast (single wave, no __syncthreads).
// ---------------------------------------------------------------------------
__global__ __launch_bounds__(64, 3) void node_k(const float* __restrict__ x,
                                                const ushort_t* __restrict__ P,
                                                const int* __restrict__ cursor,
                                                const int* __restrict__ elist,
                                                const float* __restrict__ w1,
                                                const float* __restrict__ b1,
                                                const float* __restrict__ w2t,
                                                const float* __restrict__ b2,
                                                const float* __restrict__ pxw,
                                                ushort_t* __restrict__ dh,
                                                float* __restrict__ outx) {
    const int n = blockIdx.x;
    const int lane = threadIdx.x;
    __shared__ float m_lds[64];
    const float4* mv4 = (const float4*)m_lds;

    const float4* wr = (const float4*)(w2t + lane * 64);   // w2[:,lane] contiguous
    const float4 W0 = wr[0],  W1 = wr[1],  W2 = wr[2],  W3 = wr[3];
    const float4 W4 = wr[4],  W5 = wr[5],  W6 = wr[6],  W7 = wr[7];
    const float4 W8 = wr[8],  W9 = wr[9],  W10 = wr[10], W11 = wr[11];
    const float4 W12 = wr[12], W13 = wr[13], W14 = wr[14], W15 = wr[15];

    const float w1r = w1[256 * 64 + lane];   // dist2 row of pe_w1
    const float b1v = b1[lane];
    const float b2v = b2[lane];
    const float pxv = pxw[lane];
    const float Pi = bf2f(P[(size_t)n * 128 + lane]);
    const float xi0 = x[n * 3 + 0];
    const float xi1 = x[n * 3 + 1];
    const float xi2 = x[n * 3 + 2];

    float dhacc = 0.0f;
    float dxp0 = 0.0f, dxp1 = 0.0f, dxp2 = 0.0f;
    const int dg = min(cursor[n], 64);
    const int base = n * 64;

    for (int t = 0; t < dg; t++) {
        int gj = elist[base + t];                            // wave-uniform
        float Pj = bf2f(P[(size_t)gj * 128 + 64 + lane]);
        float ddx = xi0 - x[gj * 3 + 0];
        float ddy = xi1 - x[gj * 3 + 1];
        float ddz = xi2 - x[gj * 3 + 2];
        float d2 = fmaxf(ddx * ddx + ddy * ddy + ddz * ddz, 1e-12f);
        float m = fast_silu(Pi + Pj + d2 * w1r + b1v);
        __builtin_amdgcn_wave_barrier();
        m_lds[lane] = m;
        __builtin_amdgcn_wave_barrier();
        float s0 = b2v, s1 = 0.f, s2 = 0.f, s3 = 0.f;
#define STEP(I, W)                                         \
        {                                                  \
            float4 mm = mv4[I];                            \
            s0 = fmaf(mm.x, W.x, s0);                      \
            s1 = fmaf(mm.y, W.y, s1);                      \
            s2 = fmaf(mm.z, W.z, s2);                      \
            s3 = fmaf(mm.w, W.w, s3);                      \
        }
        STEP(0, W0)  STEP(1, W1)  STEP(2, W2)  STEP(3, W3)
        STEP(4, W4)  STEP(5, W5)  STEP(6, W6)  STEP(7, W7)
        STEP(8, W8)  STEP(9, W9)  STEP(10, W10) STEP(11, W11)
        STEP(12, W12) STEP(13, W13) STEP(14, W14) STEP(15, W15)
#undef STEP
        __builtin_amdgcn_wave_barrier();
        float m2 = fast_silu((s0 + s1) + (s2 + s3));
        dhacc += m2;
        float c = m2 * pxv * fast_rcp(sqrtf(d2) + 1e-8f);
        dxp0 = fmaf(c, ddx, dxp0);
        dxp1 = fmaf(c, ddy, dxp1);
        dxp2 = fmaf(c, ddz, dxp2);
    }

    dh[(size_t)n * 64 + lane] = f2bf(dhacc);

    for (int off = 32; off; off >>= 1) {
        dxp0 += __shfl_down(dxp0, off);
        dxp1 += __shfl_down(dxp1, off);
        dxp2 += __shfl_down(dxp2, off);
    }
    if (lane == 0) {
        outx[n * 3 + 0] = xi0 + dxp0;
        outx[n * 3 + 1] = xi1 + dxp1;
        outx[n * 3 + 2] = xi2 + dxp2;
    }
}

// ---------------------------------------------------------------------------
// bf16 MFMA GEMM with PRE-TRANSPOSED bf16 weights Wt[n][k] (row stride LDW).
// 256 thr = 4 waves; block tile 128x128; wave tile 32x128 = 2x8 mfma 16x16x32.
// KPAD=40 -> 80B LDS row stride (16B aligned).
// ---------------------------------------------------------------------------
template <int KTOT, int LDW, bool A0_BF16, bool HAS_A1, bool DO_SILU,
          bool HAS_BIAS, bool HAS_RESID, bool OUT_BF16>
__global__ __launch_bounds__(256, 2) void mgemm_k(const void* __restrict__ A0v,
                                                  const ushort_t* __restrict__ A1,
                                                  const ushort_t* __restrict__ Wt,
                                                  const float* __restrict__ bias,
                                                  const float* __restrict__ resid,
                                                  void* __restrict__ outv) {
    constexpr int KPAD = 40;
    __shared__ ushort_t As[128 * KPAD];
    __shared__ ushort_t Bs[128 * KPAD];
    const int tid = threadIdx.x;
    const int m0 = blockIdx.x * 128;
    const int wave = tid >> 6;
    const int lane = tid & 63;
    const int lr = lane & 15;
    const int lq = lane >> 4;

    f32x4 acc[2][8];
#pragma unroll
    for (int mt = 0; mt < 2; mt++)
#pragma unroll
        for (int nt = 0; nt < 8; nt++) {
            f32x4 z = {0.f, 0.f, 0.f, 0.f};
            acc[mt][nt] = z;
        }

    for (int k0 = 0; k0 < KTOT; k0 += 32) {
        // stage A tile: 128 rows x 32 k (bf16 in LDS, k contiguous)
        if (A0_BF16 && !HAS_A1) {
#pragma unroll
            for (int i = 0; i < 2; i++) {
                int lin = tid + i * 256;     // 0..511
                int m = lin >> 2;            // 0..127
                int kq = (lin & 3) * 8;      // 0,8,16,24
                *(uint4*)&As[m * KPAD + kq] =
                    *(const uint4*)((const ushort_t*)A0v + (size_t)(m0 + m) * 128 + k0 + kq);
            }
        } else {
#pragma unroll
            for (int i = 0; i < 4; i++) {
                int lin = tid + i * 256;     // 0..1023
                int m = lin >> 3;            // 0..127
                int kq = (lin & 7) * 4;      // 0..28
                ushort4 w4;
                if (HAS_A1 && k0 >= 128) {
                    w4 = *(const ushort4*)(A1 + (size_t)(m0 + m) * 64 + (k0 - 128 + kq));
                } else {
                    float4 v = *(const float4*)((const float*)A0v + (size_t)(m0 + m) * 128 + k0 + kq);
                    w4.x = f2bf(v.x); w4.y = f2bf(v.y); w4.z = f2bf(v.z); w4.w = f2bf(v.w);
                }
                *(ushort4*)&As[m * KPAD + kq] = w4;
            }
        }
        // stage B tile: straight bf16 copy from Wt
#pragma unroll
        for (int i = 0; i < 2; i++) {
            int lin = tid + i * 256;
            int n = lin >> 2;
            int kq = (lin & 3) * 8;
            *(uint4*)&Bs[n * KPAD + kq] =
                *(const uint4*)(Wt + (size_t)n * LDW + k0 + kq);
        }
        __syncthreads();

        bf16x8 af[2], bfr[8];
#pragma unroll
        for (int mt = 0; mt < 2; mt++) {
            int row = wave * 32 + mt * 16 + lr;
            af[mt] = *(const bf16x8*)&As[row * KPAD + lq * 8];
        }
#pragma unroll
        for (int nt = 0; nt < 8; nt++) {
            int nn = nt * 16 + lr;
            bfr[nt] = *(const bf16x8*)&Bs[nn * KPAD + lq * 8];
        }
#pragma unroll
        for (int mt = 0; mt < 2; mt++)
#pragma unroll
            for (int nt = 0; nt < 8; nt++)
                acc[mt][nt] = __builtin_amdgcn_mfma_f32_16x16x32_bf16(
                    af[mt], bfr[nt], acc[mt][nt], 0, 0, 0);
        __syncthreads();
    }

    // epilogue
#pragma unroll
    for (int mt = 0; mt < 2; mt++) {
#pragma unroll
        for (int nt = 0; nt < 8; nt++) {
#pragma unroll
            for (int r = 0; r < 4; r++) {
                int row = m0 + wave * 32 + mt * 16 + lq * 4 + r;
                int col = nt * 16 + lr;
                float v = acc[mt][nt][r];
                if (HAS_BIAS) v += bias[col];
                if (DO_SILU) v = fast_silu(v);
                if (HAS_RESID) v += resid[(size_t)row * 128 + col];
                if (OUT_BF16)
                    ((ushort_t*)outv)[(size_t)row * 128 + col] = f2bf(v);
                else
                    ((float*)outv)[(size_t)row * 128 + col] = v;
            }
        }
    }
}

// ---------------------------------------------------------------------------
extern "C" void kernel_launch(void* const* d_in, const int* in_sizes, int n_in,
                              void* d_out, int out_size, void* d_ws, size_t ws_size,
                              hipStream_t stream) {
    const float* x     = (const float*)d_in[0];
    const float* h     = (const float*)d_in[1];
    const int*   ei    = (const int*)d_in[2];
    const float* pe_w1 = (const float*)d_in[3];
    const float* pe_b1 = (const float*)d_in[4];
    const float* pe_w2 = (const float*)d_in[5];
    const float* pe_b2 = (const float*)d_in[6];
    const float* px_w  = (const float*)d_in[7];
    const float* ph_w1 = (const float*)d_in[8];
    const float* ph_b1 = (const float*)d_in[9];
    const float* ph_w2 = (const float*)d_in[10];
    const float* ph_b2 = (const float*)d_in[11];

    float* outx = (float*)d_out;                    // 4*16384*3
    float* outh = (float*)d_out + 196608;           // 4*16384*128

    // ws layout
    ushort_t* P    = (ushort_t*)d_ws;                     // 65536*128 bf16 (reused as t)
    ushort_t* dh   = P + (size_t)65536 * 128;             // 65536*64 bf16
    int* cursor    = (int*)(dh + (size_t)65536 * 64);     // 65536 i32
    int* elist     = cursor + 65536;                      // 65536*64 i32 (16 MB)
    ushort_t* W1t  = (ushort_t*)(elist + (size_t)65536 * 64);  // 128*128 bf16
    ushort_t* Wp1t = W1t + 16384;                         // 128*192 bf16
    ushort_t* Wp2t = Wp1t + 24576;                        // 128*128 bf16
    float* w2t     = (float*)(Wp2t + 16384);              // 64*64 f32

    zero_k<<<256, 256, 0, stream>>>(cursor);
    prep_k<<<240, 256, 0, stream>>>(pe_w1, pe_w2, ph_w1, ph_w2,
                                    W1t, Wp1t, Wp2t, w2t);
    // P = h @ [W1_top | W1_mid]  (bf16 out)
    mgemm_k<128, 128, false, false, false, false, false, true>
        <<<512, 256, 0, stream>>>(h, nullptr, W1t, nullptr, nullptr, P);
    scatter_k<<<1024, 256, 0, stream>>>(ei, cursor, elist);
    node_k<<<65536, 64, 0, stream>>>(x, P, cursor, elist,
                                     pe_w1, pe_b1, w2t, pe_b2, px_w,
                                     dh, outx);
    // t = silu([h | dh] @ ph_w1 + b1)  (bf16 out, overwrites P)
    mgemm_k<192, 192, false, true, true, true, false, true>
        <<<512, 256, 0, stream>>>(h, dh, Wp1t, ph_b1, nullptr, P);
    // out_h = h + t @ ph_w2 + b2  (fp32 out)
    mgemm_k<128, 128, true, false, false, true, true, false>
        <<<512, 256, 0, stream>>>(P, nullptr, Wp2t, ph_b2, h, outh);
}